// Round 1
// baseline (18999.313 us; speedup 1.0000x reference)
//
#include <hip/hip_runtime.h>
#include <hip/hip_bf16.h>
#include <hip/hip_cooperative_groups.h>

namespace cg = cooperative_groups;

#define S_LEN   512
#define BATCH   64
#define DH      512
#define KDIM    1024      // 2*DH  (concat [h, x])
#define HIDW    8         // hidden units per WG
#define NCOLS   32        // matmul cols per WG = 4 gates * HIDW
#define WGL     64        // WGs per layer (512/8)
#define NWG     128
#define THREADS 256

typedef __attribute__((ext_vector_type(8))) unsigned short u16x8;
typedef __attribute__((ext_vector_type(8))) __bf16         bf16x8;
typedef __attribute__((ext_vector_type(4))) float          f32x4;

__device__ __forceinline__ unsigned short f2bf(float f) {
    unsigned u = __float_as_uint(f);
    unsigned r = (u + 0x7fffu + ((u >> 16) & 1u)) >> 16;   // RNE
    return (unsigned short)r;
}
__device__ __forceinline__ float sigmoid_f(float x) { return 1.f / (1.f + __expf(-x)); }
__device__ __forceinline__ float tanh_f(float x) {
    float e = __expf(2.f * x);
    return 1.f - 2.f / (e + 1.f);
}
__device__ __forceinline__ f32x4 mfma16(bf16x8 a, bf16x8 b, f32x4 c) {
    return __builtin_amdgcn_mfma_f32_16x16x32_bf16(a, b, c, 0, 0, 0);
}

// ws layout (elements of unsigned short / bf16):
//   hx[0][0] : ws + 0            [64][1024]   layer0 input (parity 0)
//   hx[0][1] : ws + 65536
//   hx[1][0] : ws + 131072                    layer1 input
//   hx[1][1] : ws + 196608
// cols [0,512) = h-part, [512,1024) = x-part.

__global__ void lstm_init(const float* __restrict__ seq,
                          const float* __restrict__ h_init,
                          unsigned short* __restrict__ ws) {
    int i = blockIdx.x * blockDim.x + threadIdx.x;   // 0 .. 32767 (= BATCH*DH)
    if (i < BATCH * DH) {
        int row = i >> 9;
        int col = i & 511;
        // hx[0][0]: h-part = h_init[0], x-part = seq[0]
        ws[(size_t)row * KDIM + col]      = f2bf(h_init[i]);
        ws[(size_t)row * KDIM + DH + col] = f2bf(seq[i]);
        // hx[1][1]: h-part = h_init[1]  (first read by layer1 at it=1)
        ws[(size_t)(3 * BATCH * KDIM) + (size_t)row * KDIM + col] =
            f2bf(h_init[(size_t)BATCH * DH + i]);
    }
}

__global__ __launch_bounds__(THREADS, 1)
void lstm_main(const float* __restrict__ seq,
               const float* __restrict__ Wf, const float* __restrict__ Bf,
               const float* __restrict__ Wi, const float* __restrict__ Bi,
               const float* __restrict__ Wc, const float* __restrict__ Bc,
               const float* __restrict__ Wo, const float* __restrict__ Bo,
               float* __restrict__ out, unsigned short* __restrict__ ws)
{
    __shared__ unsigned short wlds[NCOLS * KDIM];   // 64 KB, [mcol][k] bf16, swizzled

    const int wg    = blockIdx.x;
    const int layer = (wg >= WGL) ? 1 : 0;
    const int wid   = layer ? wg - WGL : wg;
    const int jbase = wid * HIDW;
    const int tid   = threadIdx.x;
    const int lane  = tid & 63;
    const int wave  = tid >> 6;

    unsigned short* hx[2][2];
    hx[0][0] = ws;
    hx[0][1] = ws + (size_t)BATCH * KDIM;
    hx[1][0] = ws + (size_t)2 * BATCH * KDIM;
    hx[1][1] = ws + (size_t)3 * BATCH * KDIM;

    // ---- stage weights into LDS once (bf16, XOR-swizzled) ----
    {
        const size_t woff = (size_t)layer * KDIM * DH;
        const float* Wg[4] = { Wf + woff, Wi + woff, Wc + woff, Wo + woff };
        for (int idx = tid; idx < NCOLS * KDIM; idx += THREADS) {
            int mcol = idx & (NCOLS - 1);
            int k    = idx >> 5;
            int gate = mcol >> 3;                 // 0=f 1=i 2=c 3=o
            int j    = jbase + (mcol & 7);
            float w  = Wg[gate][(size_t)k * DH + j];
            unsigned byte = (unsigned)(mcol * (KDIM * 2) + k * 2);
            byte ^= ((unsigned)(mcol & 7) << 4);
            wlds[byte >> 1] = f2bf(w);
        }
    }
    const int   jl = jbase + (lane & 7);
    const float bF = Bf[layer * DH + jl];
    const float bI = Bi[layer * DH + jl];
    const float bC = Bc[layer * DH + jl];
    const float bO = Bo[layer * DH + jl];

    __syncthreads();

    const int  arow  = wave * 16 + (lane & 15);        // A-fragment row (batch idx)
    const int  crow0 = wave * 16 + ((lane >> 4) << 2); // C-fragment first row
    const int  koff  = (lane >> 4) * 8;                // k offset within K=32 chunk
    const bool isLow = (lane & 8) == 0;                // lane holds f / c~ (else i / o)

    float cs0 = 0.f, cs1 = 0.f, cs2 = 0.f, cs3 = 0.f;  // cell state (c0 = zeros)

    cg::grid_group grid = cg::this_grid();

    const unsigned mc0 = lane & 15;
    const unsigned mc1 = mc0 + 16;
    const unsigned sw  = (mc0 & 7) << 4;
    const unsigned koff2 = (unsigned)koff * 2;

    for (int it = 0; it <= S_LEN; ++it) {
        const bool active = layer ? (it >= 1) : (it < S_LEN);
        const int  t      = layer ? it - 1 : it;

        if (active) {
            const unsigned short* hxin = hx[layer][it & 1];
            const unsigned short* ap   = hxin + (size_t)arow * KDIM + koff;

            f32x4 a00 = {0,0,0,0}, a01 = {0,0,0,0};
            f32x4 a10 = {0,0,0,0}, a11 = {0,0,0,0};

            #pragma unroll 8
            for (int s = 0; s < 32; ++s) {
                bf16x8 av = __builtin_bit_cast(bf16x8, *(const u16x8*)(ap + s * 32));
                unsigned kb = (unsigned)s * 64 + koff2;
                bf16x8 w0 = __builtin_bit_cast(bf16x8,
                    *(const u16x8*)((const char*)wlds + ((mc0 * 2048u + kb) ^ sw)));
                bf16x8 w1 = __builtin_bit_cast(bf16x8,
                    *(const u16x8*)((const char*)wlds + ((mc1 * 2048u + kb) ^ sw)));
                if (s & 1) { a01 = mfma16(av, w0, a01); a11 = mfma16(av, w1, a11); }
                else       { a00 = mfma16(av, w0, a00); a10 = mfma16(av, w1, a10); }
            }
            f32x4 pA = a00 + a01;   // f (lanes c<8) / i (lanes c>=8) preacts
            f32x4 pB = a10 + a11;   // c~ / o preacts

            float hv[4];
            float csv[4] = { cs0, cs1, cs2, cs3 };
            #pragma unroll
            for (int r = 0; r < 4; ++r) {
                float sa = pA[r], sb = pB[r];
                float qa = __shfl_xor(sa, 8, 64);
                float qb = __shfl_xor(sb, 8, 64);
                float fpre = (isLow ? sa : qa) + bF;
                float ipre = (isLow ? qa : sa) + bI;
                float cpre = (isLow ? sb : qb) + bC;
                float opre = (isLow ? qb : sb) + bO;
                float fg = sigmoid_f(fpre);
                float ig = sigmoid_f(ipre);
                float ct = tanh_f(cpre);
                float og = sigmoid_f(opre);
                float cn = fg * csv[r] + ig * ct;
                csv[r] = cn;
                hv[r]  = og * tanh_f(cn);
            }
            cs0 = csv[0]; cs1 = csv[1]; cs2 = csv[2]; cs3 = csv[3];

            unsigned short* nxt_self = hx[layer][(it + 1) & 1];
            if (isLow) {
                #pragma unroll
                for (int r = 0; r < 4; ++r) {
                    const int row = crow0 + r;
                    const unsigned short hb = f2bf(hv[r]);
                    nxt_self[(size_t)row * KDIM + jl] = hb;           // own h-part
                    if (!layer) {
                        // feed layer1's x-part for next iteration
                        hx[1][(it + 1) & 1][(size_t)row * KDIM + DH + jl] = hb;
                        if (t == S_LEN - 1)
                            out[(size_t)S_LEN * BATCH * DH + (size_t)row * DH + jl] = hv[r];
                    } else {
                        out[(size_t)t * BATCH * DH + (size_t)row * DH + jl] = hv[r];
                        if (t == S_LEN - 1)
                            out[(size_t)S_LEN * BATCH * DH + (size_t)BATCH * DH
                                + (size_t)row * DH + jl] = hv[r];
                    }
                }
            }
        }

        // layer1 WGs double as x-converters: seq[it+1] -> hx[0][(it+1)&1] x-part
        if (layer && (it + 1) < S_LEN) {
            const float* sp = seq + (size_t)(it + 1) * BATCH * DH;
            unsigned short* dp = hx[0][(it + 1) & 1];
            const int base = (wid * THREADS + tid) * 2;   // 0..32766
            const int row = base >> 9;
            const int col = base & 511;
            float2 v = *(const float2*)(sp + base);
            dp[(size_t)row * KDIM + DH + col]     = f2bf(v.x);
            dp[(size_t)row * KDIM + DH + col + 1] = f2bf(v.y);
        }

        __threadfence();
        grid.sync();
    }
}

extern "C" void kernel_launch(void* const* d_in, const int* in_sizes, int n_in,
                              void* d_out, int out_size, void* d_ws, size_t ws_size,
                              hipStream_t stream) {
    const float* seq    = (const float*)d_in[0];
    const float* h_init = (const float*)d_in[1];
    const float* Wf     = (const float*)d_in[2];
    const float* Bf     = (const float*)d_in[3];
    const float* Wi     = (const float*)d_in[4];
    const float* Bi     = (const float*)d_in[5];
    const float* Wc     = (const float*)d_in[6];
    const float* Bc     = (const float*)d_in[7];
    const float* Wo     = (const float*)d_in[8];
    const float* Bo     = (const float*)d_in[9];
    float* out          = (float*)d_out;
    unsigned short* ws  = (unsigned short*)d_ws;

    hipLaunchKernelGGL(lstm_init, dim3(128), dim3(THREADS), 0, stream, seq, h_init, ws);

    void* args[] = { (void*)&seq,
                     (void*)&Wf, (void*)&Bf,
                     (void*)&Wi, (void*)&Bi,
                     (void*)&Wc, (void*)&Bc,
                     (void*)&Wo, (void*)&Bo,
                     (void*)&out, (void*)&ws };
    hipLaunchCooperativeKernel((void*)lstm_main, dim3(NWG), dim3(THREADS),
                               args, 0, stream);
}

// Round 2
// 9804.968 us; speedup vs baseline: 1.9377x; 1.9377x over previous
//
#include <hip/hip_runtime.h>
#include <hip/hip_bf16.h>

#define S_LEN   512
#define BATCH   64
#define DH      512
#define KDIM    1024      // 2*DH (concat [h, x])
#define NCOLS   64        // 4 gates * 16 hidden units per WG
#define WGL     32        // WGs per layer
#define NWG     64
#define THREADS 256
#define LDS_BYTES (NCOLS * KDIM * 2)   // 131072 B weights per WG

typedef __attribute__((ext_vector_type(8))) unsigned short u16x8;
typedef __attribute__((ext_vector_type(8))) __bf16         bf16x8;
typedef __attribute__((ext_vector_type(4))) float          f32x4;

__device__ __forceinline__ unsigned short f2bf(float f) {
    unsigned u = __float_as_uint(f);
    return (unsigned short)((u + 0x7fffu + ((u >> 16) & 1u)) >> 16);   // RNE
}
__device__ __forceinline__ float sigmoid_f(float x) { return 1.f / (1.f + __expf(-x)); }
__device__ __forceinline__ float tanh_f(float x) {
    float e = __expf(2.f * x);
    return 1.f - 2.f / (e + 1.f);
}
__device__ __forceinline__ f32x4 mfma16(bf16x8 a, bf16x8 b, f32x4 c) {
    return __builtin_amdgcn_mfma_f32_16x16x32_bf16(a, b, c, 0, 0, 0);
}

// ws layout (bytes):
//   0       : h0buf [2][64][512]  bf16   (131072)   layer0 h ping-pong
//   131072  : hx1buf[2][64][1024] bf16   (262144)   layer1 [h,x] ping-pong
//   393216  : bar[520] uint                          per-iteration barrier slots

#define WS_H0    0
#define WS_HX1   (2 * BATCH * DH)            // in ushorts
#define WS_BAR_B 393216                      // byte offset

__global__ void lstm_init(const float* __restrict__ seq,
                          const float* __restrict__ h_init,
                          unsigned short* __restrict__ ws) {
    int i = blockIdx.x * blockDim.x + threadIdx.x;   // 0 .. 32767
    unsigned* bar = (unsigned*)((char*)ws + WS_BAR_B);
    if (i < 520) bar[i] = 0;
    if (i < BATCH * DH) {
        int row = i >> 9;
        int col = i & 511;
        // h0buf[par=0] <- h_init[layer0]   (read by layer0 at it=0)
        ws[WS_H0 + row * DH + col] = f2bf(h_init[i]);
        // hx1buf[par=1] h-part <- h_init[layer1]  (read by layer1 at it=1)
        ws[WS_HX1 + BATCH * KDIM + row * KDIM + col] =
            f2bf(h_init[(size_t)BATCH * DH + i]);
    }
}

__global__ __launch_bounds__(THREADS, 1)
void lstm_main(const float* __restrict__ seq,
               const float* __restrict__ Wf, const float* __restrict__ Bf,
               const float* __restrict__ Wi, const float* __restrict__ Bi,
               const float* __restrict__ Wc, const float* __restrict__ Bc,
               const float* __restrict__ Wo, const float* __restrict__ Bo,
               float* __restrict__ out, unsigned short* __restrict__ ws)
{
    extern __shared__ unsigned short wlds[];   // [NCOLS][KDIM] bf16, XOR-swizzled

    const int wg    = blockIdx.x;
    const int layer = (wg >= WGL) ? 1 : 0;
    const int wid   = layer ? wg - WGL : wg;
    const int jbase = wid * 16;
    const int tid   = threadIdx.x;
    const int lane  = tid & 63;
    const int wave  = tid >> 6;

    unsigned short* h0b  = ws + WS_H0;
    unsigned short* hx1b = ws + WS_HX1;
    unsigned* bar = (unsigned*)((char*)ws + WS_BAR_B);

    // ---- stage this WG's weight slice into LDS (bf16, swizzled), once ----
    {
        const size_t woff = (size_t)layer * KDIM * DH;
        const float* Wg[4] = { Wf + woff, Wi + woff, Wc + woff, Wo + woff };
        for (int idx = tid; idx < NCOLS * KDIM; idx += THREADS) {
            int mcol = idx & (NCOLS - 1);          // col-tile*16+unit; tile==gate
            int k    = idx >> 6;
            float w  = Wg[mcol >> 4][(size_t)k * DH + jbase + (mcol & 15)];
            unsigned byte = ((unsigned)mcol * 2048u + (unsigned)k * 2u)
                          ^ (((unsigned)mcol & 7u) << 4);
            wlds[byte >> 1] = f2bf(w);
        }
    }
    const int   u    = lane & 15;                  // hidden unit within WG
    const int   jcol = jbase + u;                  // global hidden col
    const float bF = Bf[layer * DH + jcol];
    const float bI = Bi[layer * DH + jcol];
    const float bC = Bc[layer * DH + jcol];
    const float bO = Bo[layer * DH + jcol];
    __syncthreads();

    const int arow  = wave * 16 + (lane & 15);         // A row (batch idx)
    const int crow0 = wave * 16 + ((lane >> 4) << 2);  // C first row
    const int koff  = (lane >> 4) * 8;                 // k offset in K=32 chunk
    const unsigned sw = ((unsigned)(lane & 7)) << 4;   // LDS swizzle bits
    const unsigned wb0 = (0 * 16 + (unsigned)u) * 2048u;   // f
    const unsigned wb1 = (1 * 16 + (unsigned)u) * 2048u;   // i
    const unsigned wb2 = (2 * 16 + (unsigned)u) * 2048u;   // c~
    const unsigned wb3 = (3 * 16 + (unsigned)u) * 2048u;   // o

    float cs[4] = {0.f, 0.f, 0.f, 0.f};

    for (int it = 0; it <= S_LEN; ++it) {
        const bool active = layer ? (it >= 1) : (it < S_LEN);
        const int  t      = layer ? it - 1 : it;

        if (active) {
            const int par = it & 1;
            f32x4 aA0 = {0,0,0,0}, aA1 = {0,0,0,0}, aA2 = {0,0,0,0}, aA3 = {0,0,0,0};
            f32x4 aB0 = {0,0,0,0}, aB1 = {0,0,0,0}, aB2 = {0,0,0,0}, aB3 = {0,0,0,0};

            const unsigned short* hbase = layer
                ? (hx1b + par * BATCH * KDIM + arow * KDIM + koff)
                : (h0b  + par * BATCH * DH   + arow * DH   + koff);
            const float* sp = seq + ((size_t)t * BATCH + arow) * DH + koff;

            #pragma unroll 4
            for (int s = 0; s < 32; ++s) {
                bf16x8 av;
                if (!layer && s >= 16) {
                    // x-part straight from seq (fp32, L2-cacheable)
                    float4 v0 = *(const float4*)(sp + (s - 16) * 32);
                    float4 v1 = *(const float4*)(sp + (s - 16) * 32 + 4);
                    u16x8 tv;
                    tv[0]=f2bf(v0.x); tv[1]=f2bf(v0.y); tv[2]=f2bf(v0.z); tv[3]=f2bf(v0.w);
                    tv[4]=f2bf(v1.x); tv[5]=f2bf(v1.y); tv[6]=f2bf(v1.z); tv[7]=f2bf(v1.w);
                    av = __builtin_bit_cast(bf16x8, tv);
                } else {
                    av = __builtin_bit_cast(bf16x8, *(const u16x8*)(hbase + s * 32));
                }
                const unsigned kb = ((unsigned)s * 64u + (unsigned)koff * 2u) ^ sw;
                bf16x8 w0 = __builtin_bit_cast(bf16x8, *(const u16x8*)((const char*)wlds + wb0 + kb));
                bf16x8 w1 = __builtin_bit_cast(bf16x8, *(const u16x8*)((const char*)wlds + wb1 + kb));
                bf16x8 w2 = __builtin_bit_cast(bf16x8, *(const u16x8*)((const char*)wlds + wb2 + kb));
                bf16x8 w3 = __builtin_bit_cast(bf16x8, *(const u16x8*)((const char*)wlds + wb3 + kb));
                if (s & 1) {
                    aB0 = mfma16(av, w0, aB0); aB1 = mfma16(av, w1, aB1);
                    aB2 = mfma16(av, w2, aB2); aB3 = mfma16(av, w3, aB3);
                } else {
                    aA0 = mfma16(av, w0, aA0); aA1 = mfma16(av, w1, aA1);
                    aA2 = mfma16(av, w2, aA2); aA3 = mfma16(av, w3, aA3);
                }
            }

            // f,i,c~,o for unit u live in the SAME lane -> no cross-lane combine
            const int npar = (it + 1) & 1;
            #pragma unroll
            for (int r = 0; r < 4; ++r) {
                float fg = sigmoid_f(aA0[r] + aB0[r] + bF);
                float ig = sigmoid_f(aA1[r] + aB1[r] + bI);
                float ct = tanh_f  (aA2[r] + aB2[r] + bC);
                float og = sigmoid_f(aA3[r] + aB3[r] + bO);
                float cn = fg * cs[r] + ig * ct;
                cs[r] = cn;
                float hv = og * tanh_f(cn);
                const int row = crow0 + r;
                const unsigned short hb = f2bf(hv);
                if (!layer) {
                    h0b [npar * BATCH * DH   + row * DH   + jcol]      = hb;
                    hx1b[npar * BATCH * KDIM + row * KDIM + DH + jcol] = hb;
                    if (t == S_LEN - 1)
                        out[(size_t)S_LEN * BATCH * DH + (size_t)row * DH + jcol] = hv;
                } else {
                    hx1b[npar * BATCH * KDIM + row * KDIM + jcol] = hb;
                    out[((size_t)t * BATCH + row) * DH + jcol] = hv;
                    if (t == S_LEN - 1)
                        out[(size_t)S_LEN * BATCH * DH + (size_t)BATCH * DH
                            + (size_t)row * DH + jcol] = hv;
                }
            }
        }

        // ---- lightweight device-scope barrier ----
        if (it < S_LEN) {
            __syncthreads();                       // drains each wave's vmcnt
            if (tid == 0) {
                __builtin_amdgcn_fence(__ATOMIC_RELEASE, "agent");   // wbl2: WG stores -> L3
                __hip_atomic_fetch_add(&bar[it], 1u, __ATOMIC_RELAXED,
                                       __HIP_MEMORY_SCOPE_AGENT);
                while (__hip_atomic_load(&bar[it], __ATOMIC_RELAXED,
                                         __HIP_MEMORY_SCOPE_AGENT) < NWG)
                    __builtin_amdgcn_s_sleep(2);
            }
            __syncthreads();
            __builtin_amdgcn_fence(__ATOMIC_ACQUIRE, "agent");       // inv: drop stale L1/L2
        }
    }
}

extern "C" void kernel_launch(void* const* d_in, const int* in_sizes, int n_in,
                              void* d_out, int out_size, void* d_ws, size_t ws_size,
                              hipStream_t stream) {
    const float* seq    = (const float*)d_in[0];
    const float* h_init = (const float*)d_in[1];
    const float* Wf     = (const float*)d_in[2];
    const float* Bf     = (const float*)d_in[3];
    const float* Wi     = (const float*)d_in[4];
    const float* Bi     = (const float*)d_in[5];
    const float* Wc     = (const float*)d_in[6];
    const float* Bc     = (const float*)d_in[7];
    const float* Wo     = (const float*)d_in[8];
    const float* Bo     = (const float*)d_in[9];
    float* out          = (float*)d_out;
    unsigned short* ws  = (unsigned short*)d_ws;

    hipFuncSetAttribute((const void*)lstm_main,
                        hipFuncAttributeMaxDynamicSharedMemorySize, LDS_BYTES);

    hipLaunchKernelGGL(lstm_init, dim3(128), dim3(THREADS), 0, stream, seq, h_init, ws);

    void* args[] = { (void*)&seq,
                     (void*)&Wf, (void*)&Bf,
                     (void*)&Wi, (void*)&Bi,
                     (void*)&Wc, (void*)&Bc,
                     (void*)&Wo, (void*)&Bo,
                     (void*)&out, (void*)&ws };
    hipLaunchCooperativeKernel((void*)lstm_main, dim3(NWG), dim3(THREADS),
                               args, LDS_BYTES, stream);
}

// Round 5
// 9246.056 us; speedup vs baseline: 2.0549x; 1.0604x over previous
//
#include <hip/hip_runtime.h>
#include <hip/hip_bf16.h>

#define S_LEN   512
#define BATCH   64
#define DH      512
#define KDIM    1024      // 2*DH (concat [h, x])
#define NCOLS   64        // 4 gates * 16 hidden units per WG
#define WGL     32        // WGs per layer
#define NWG     64
#define THREADS 256
#define LDS_BYTES (NCOLS * KDIM * 2)   // 131072 B weights per WG

typedef __attribute__((ext_vector_type(8))) unsigned short u16x8;
typedef __attribute__((ext_vector_type(8))) __bf16         bf16x8;
typedef __attribute__((ext_vector_type(4))) float          f32x4;

__device__ __forceinline__ unsigned short f2bf(float f) {
    unsigned u = __float_as_uint(f);
    return (unsigned short)((u + 0x7fffu + ((u >> 16) & 1u)) >> 16);   // RNE
}
__device__ __forceinline__ float sigmoid_f(float x) { return 1.f / (1.f + __expf(-x)); }
__device__ __forceinline__ float tanh_f(float x) {
    float e = __expf(2.f * x);
    return 1.f - 2.f / (e + 1.f);
}
__device__ __forceinline__ f32x4 mfma16(bf16x8 a, bf16x8 b, f32x4 c) {
    return __builtin_amdgcn_mfma_f32_16x16x32_bf16(a, b, c, 0, 0, 0);
}

// ws layout:
//   ushort[0]      : h0buf [2][64][512]  bf16    layer0 h ping-pong
//   ushort[65536]  : hx1buf[2][64][1024] bf16    layer1 [h,x] ping-pong
//   byte 393216    : flags[64] uint              per-WG monotonic barrier flags
#define WS_H0    0
#define WS_HX1   (2 * BATCH * DH)
#define WS_BAR_B 393216

__global__ void lstm_init(const float* __restrict__ seq,
                          const float* __restrict__ h_init,
                          unsigned short* __restrict__ ws) {
    int i = blockIdx.x * blockDim.x + threadIdx.x;   // 0 .. 32767
    unsigned* flags = (unsigned*)((char*)ws + WS_BAR_B);
    if (i < NWG) flags[i] = 0;                       // re-zeroed every launch
    if (i < BATCH * DH) {
        int row = i >> 9;
        int col = i & 511;
        ws[WS_H0 + row * DH + col] = f2bf(h_init[i]);                    // h0 par0
        ws[WS_HX1 + BATCH * KDIM + row * KDIM + col] =                   // hx1 par1 h-part
            f2bf(h_init[(size_t)BATCH * DH + i]);
    }
}

__global__ __launch_bounds__(THREADS, 1)
void lstm_main(const float* __restrict__ seq,
               const float* __restrict__ Wf, const float* __restrict__ Bf,
               const float* __restrict__ Wi, const float* __restrict__ Bi,
               const float* __restrict__ Wc, const float* __restrict__ Bc,
               const float* __restrict__ Wo, const float* __restrict__ Bo,
               float* __restrict__ out, unsigned short* __restrict__ ws)
{
    extern __shared__ unsigned short wlds[];   // [NCOLS][KDIM] bf16, XOR-swizzled

    const int wg    = blockIdx.x;
    const int layer = (wg >= WGL) ? 1 : 0;
    const int wid   = layer ? wg - WGL : wg;
    const int jbase = wid * 16;
    const int tid   = threadIdx.x;
    const int lane  = tid & 63;
    const int wave  = tid >> 6;

    unsigned short* h0b  = ws + WS_H0;
    unsigned short* hx1b = ws + WS_HX1;
    unsigned* flags = (unsigned*)((char*)ws + WS_BAR_B);

    // ---- stage this WG's weight slice into LDS (bf16, swizzled), once ----
    {
        const size_t woff = (size_t)layer * KDIM * DH;
        const float* Wg[4] = { Wf + woff, Wi + woff, Wc + woff, Wo + woff };
        for (int idx = tid; idx < NCOLS * KDIM; idx += THREADS) {
            int mcol = idx & (NCOLS - 1);          // gate*16 + unit
            int k    = idx >> 6;
            float w  = Wg[mcol >> 4][(size_t)k * DH + jbase + (mcol & 15)];
            unsigned byte = ((unsigned)mcol * 2048u + (unsigned)k * 2u)
                          ^ (((unsigned)mcol & 7u) << 4);
            wlds[byte >> 1] = f2bf(w);
        }
    }
    const int   u    = lane & 15;
    const int   jcol = jbase + u;
    const float bF = Bf[layer * DH + jcol];
    const float bI = Bi[layer * DH + jcol];
    const float bC = Bc[layer * DH + jcol];
    const float bO = Bo[layer * DH + jcol];
    __syncthreads();

    const int arow  = wave * 16 + (lane & 15);         // A row (batch idx)
    const int crow0 = wave * 16 + ((lane >> 4) << 2);  // C first row
    const int koff  = (lane >> 4) * 8;                 // k offset in K=32 chunk
    const unsigned sw = ((unsigned)(lane & 7)) << 4;
    const unsigned wb0 = (0u * 16 + (unsigned)u) * 2048u;
    const unsigned wb1 = (1u * 16 + (unsigned)u) * 2048u;
    const unsigned wb2 = (2u * 16 + (unsigned)u) * 2048u;
    const unsigned wb3 = (3u * 16 + (unsigned)u) * 2048u;

    float cs[4] = {0.f, 0.f, 0.f, 0.f};

    for (int it = 0; it <= S_LEN; ++it) {
        const bool active = layer ? (it >= 1) : (it < S_LEN);
        const int  t      = layer ? it - 1 : it;

        if (active) {
            const int par = it & 1;
            f32x4 aA0 = {0,0,0,0}, aA1 = {0,0,0,0}, aA2 = {0,0,0,0}, aA3 = {0,0,0,0};
            f32x4 aB0 = {0,0,0,0}, aB1 = {0,0,0,0}, aB2 = {0,0,0,0}, aB3 = {0,0,0,0};

            const unsigned short* hbase = layer
                ? (hx1b + par * BATCH * KDIM + arow * KDIM + koff)
                : (h0b  + par * BATCH * DH   + arow * DH   + koff);
            const float* sp = seq + ((size_t)t * BATCH + arow) * DH + koff;

            #pragma unroll 4
            for (int s = 0; s < 32; ++s) {
                bf16x8 av;
                if (!layer && s >= 16) {
                    // x-part straight from seq (fp32, L2-cacheable, read-only)
                    float4 v0 = *(const float4*)(sp + (s - 16) * 32);
                    float4 v1 = *(const float4*)(sp + (s - 16) * 32 + 4);
                    u16x8 tv;
                    tv[0]=f2bf(v0.x); tv[1]=f2bf(v0.y); tv[2]=f2bf(v0.z); tv[3]=f2bf(v0.w);
                    tv[4]=f2bf(v1.x); tv[5]=f2bf(v1.y); tv[6]=f2bf(v1.z); tv[7]=f2bf(v1.w);
                    av = __builtin_bit_cast(bf16x8, tv);
                } else {
                    av = __builtin_bit_cast(bf16x8, *(const u16x8*)(hbase + s * 32));
                }
                const unsigned kb = ((unsigned)s * 64u + (unsigned)koff * 2u) ^ sw;
                bf16x8 w0 = __builtin_bit_cast(bf16x8, *(const u16x8*)((const char*)wlds + wb0 + kb));
                bf16x8 w1 = __builtin_bit_cast(bf16x8, *(const u16x8*)((const char*)wlds + wb1 + kb));
                bf16x8 w2 = __builtin_bit_cast(bf16x8, *(const u16x8*)((const char*)wlds + wb2 + kb));
                bf16x8 w3 = __builtin_bit_cast(bf16x8, *(const u16x8*)((const char*)wlds + wb3 + kb));
                if (s & 1) {
                    aB0 = mfma16(av, w0, aB0); aB1 = mfma16(av, w1, aB1);
                    aB2 = mfma16(av, w2, aB2); aB3 = mfma16(av, w3, aB3);
                } else {
                    aA0 = mfma16(av, w0, aA0); aA1 = mfma16(av, w1, aA1);
                    aA2 = mfma16(av, w2, aA2); aA3 = mfma16(av, w3, aA3);
                }
            }

            const int npar = (it + 1) & 1;
            #pragma unroll
            for (int r = 0; r < 4; ++r) {
                float fg = sigmoid_f(aA0[r] + aB0[r] + bF);
                float ig = sigmoid_f(aA1[r] + aB1[r] + bI);
                float ct = tanh_f  (aA2[r] + aB2[r] + bC);
                float og = sigmoid_f(aA3[r] + aB3[r] + bO);
                float cn = fg * cs[r] + ig * ct;
                cs[r] = cn;
                float hv = og * tanh_f(cn);
                const int row = crow0 + r;
                const unsigned short hb16 = f2bf(hv);
                if (!layer) {
                    // normal cached stores; release-wbl2 at the barrier flushes them
                    h0b [npar * BATCH * DH   + row * DH   + jcol]      = hb16;
                    hx1b[npar * BATCH * KDIM + row * KDIM + DH + jcol] = hb16;
                    if (t == S_LEN - 1)
                        __builtin_nontemporal_store(hv,
                            out + (size_t)S_LEN * BATCH * DH + (size_t)row * DH + jcol);
                } else {
                    hx1b[npar * BATCH * KDIM + row * KDIM + jcol] = hb16;
                    __builtin_nontemporal_store(hv,
                        out + ((size_t)t * BATCH + row) * DH + jcol);
                    if (t == S_LEN - 1)
                        __builtin_nontemporal_store(hv,
                            out + (size_t)S_LEN * BATCH * DH + (size_t)BATCH * DH
                                + (size_t)row * DH + jcol);
                }
            }
        }

        // ---- flag-array device barrier (r2 semantics, cheaper mechanics) ----
        if (it < S_LEN) {
            __syncthreads();   // all 4 waves' stores drained (vmcnt0) & in L2
            if (wave == 0) {
                if (lane == 0) {
                    // RELEASE store: s_waitcnt + buffer_wbl2(agent) + store ->
                    // all of this WG's L2-resident stores reach the coherence
                    // point before the flag is visible.
                    __hip_atomic_store(&flags[wg], (unsigned)(it + 1),
                                       __ATOMIC_RELEASE, __HIP_MEMORY_SCOPE_AGENT);
                }
                // one per-lane load per poll: lane i watches WG i
                unsigned v;
                do {
                    __builtin_amdgcn_s_sleep(1);
                    v = __hip_atomic_load(&flags[lane], __ATOMIC_RELAXED,
                                          __HIP_MEMORY_SCOPE_AGENT);
                } while (!__all((int)(v >= (unsigned)(it + 1))));
                // ACQUIRE: invalidate L1+L2 once per WG (L1 is per-CU, shared
                // by all 4 waves; L2 per-XCD) before anyone loads new h.
                __builtin_amdgcn_fence(__ATOMIC_ACQUIRE, "agent");
            }
            __syncthreads();
        }
    }
}

extern "C" void kernel_launch(void* const* d_in, const int* in_sizes, int n_in,
                              void* d_out, int out_size, void* d_ws, size_t ws_size,
                              hipStream_t stream) {
    const float* seq    = (const float*)d_in[0];
    const float* h_init = (const float*)d_in[1];
    const float* Wf     = (const float*)d_in[2];
    const float* Bf     = (const float*)d_in[3];
    const float* Wi     = (const float*)d_in[4];
    const float* Bi     = (const float*)d_in[5];
    const float* Wc     = (const float*)d_in[6];
    const float* Bc     = (const float*)d_in[7];
    const float* Wo     = (const float*)d_in[8];
    const float* Bo     = (const float*)d_in[9];
    float* out          = (float*)d_out;
    unsigned short* ws  = (unsigned short*)d_ws;

    hipFuncSetAttribute((const void*)lstm_main,
                        hipFuncAttributeMaxDynamicSharedMemorySize, LDS_BYTES);

    hipLaunchKernelGGL(lstm_init, dim3(128), dim3(THREADS), 0, stream, seq, h_init, ws);

    void* args[] = { (void*)&seq,
                     (void*)&Wf, (void*)&Bf,
                     (void*)&Wi, (void*)&Bi,
                     (void*)&Wc, (void*)&Bc,
                     (void*)&Wo, (void*)&Bo,
                     (void*)&out, (void*)&ws };
    hipLaunchCooperativeKernel((void*)lstm_main, dim3(NWG), dim3(THREADS),
                               args, LDS_BYTES, stream);
}